// Round 15
// baseline (73.334 us; speedup 1.0000x reference)
//
#include <hip/hip_runtime.h>
#include <string.h>

// Segmented argmax (first-max tie-break), exact, R10/R14 structure:
//  1. seed: stream pred; edges >= t gather dst sparsely, u64-atomicMax into
//     tbl (unfiltered — atomics overlap the stream, R12 proved filters hurt).
//  2. bitmap: bit i = (tbl[i]>>32) >= t; thread 0 zeroes `found`.
//  3. main: high edge -> done in seed; low edge to seeded node -> LDS-bitmap
//     skip; low edge to unseeded node -> shd plain-store-throttled filter +
//     atomic.
//  4. node epilogue.
// Exactness: every >=t edge reaches the u64 atomicMax; skips require
// pred < t <= truemax (bitmap) or pred < shd <= truemax (slow path); equality
// always proceeds -> min-index tie-break via ~idx low word.
//
// R15 experiment (last lever): CH=8 with ALL stream loads issued upfront
// (128 B/lane in flight in main), block=256. R13's CH=8 was confounded
// (loads moved inside the loop); R7's MLP test was masked by 12.8M random
// loads. If this is null, ~3.5 TB/s is the scan wall -> declare ceiling.

typedef float fx4 __attribute__((ext_vector_type(4)));
typedef int   ix4 __attribute__((ext_vector_type(4)));

#define CH 8    // vec4 chunks per thread (32 edges), loads issued upfront

__device__ __forceinline__ unsigned long long pack64(unsigned pbits, unsigned i) {
    return ((unsigned long long)pbits << 32) |
           (unsigned long long)(0xFFFFFFFFu - i);
}

__device__ __forceinline__ unsigned shadow_ld(const unsigned* p) {
    return __hip_atomic_load(p, __ATOMIC_RELAXED, __HIP_MEMORY_SCOPE_WORKGROUP);
}
__device__ __forceinline__ void shadow_st(unsigned* p, unsigned v) {
    __hip_atomic_store(p, v, __ATOMIC_RELAXED, __HIP_MEMORY_SCOPE_WORKGROUP);
}

// Pass 1: pred-only stream (8 loads upfront); high edges gather dst, atomic.
__global__ void seed_pass(const float* __restrict__ pred,
                          const int* __restrict__ dst,
                          unsigned long long* __restrict__ tbl,
                          int e, unsigned tbits) {
    const int nvec = e >> 2;
    const int T = gridDim.x * blockDim.x;
    const int t = blockIdx.x * blockDim.x + threadIdx.x;

    fx4 p[CH];
    int vi[CH];
    bool ok[CH];
    #pragma unroll
    for (int c = 0; c < CH; ++c) {
        vi[c] = t + c * T;
        ok[c] = vi[c] < nvec;
        p[c] = ((const fx4*)pred)[ok[c] ? vi[c] : 0];
    }
    #pragma unroll
    for (int c = 0; c < CH; ++c) {
        unsigned pbv[4] = {__float_as_uint(p[c].x), __float_as_uint(p[c].y),
                           __float_as_uint(p[c].z), __float_as_uint(p[c].w)};
        unsigned base = (unsigned)(vi[c] << 2);
        #pragma unroll
        for (int k = 0; k < 4; ++k) {
            if (ok[c] && pbv[k] >= tbits) {
                int d = dst[base + k];              // sparse gather (~3%)
                (void)__hip_atomic_fetch_max(&tbl[d], pack64(pbv[k], base + k),
                                             __ATOMIC_RELAXED,
                                             __HIP_MEMORY_SCOPE_AGENT);
            }
        }
    }
}

// Pass 2: bitmap from tbl; thread 0 zeroes `found`.
__global__ void bitmap_pass(const unsigned long long* __restrict__ tbl,
                            unsigned long long* __restrict__ bmp,
                            float* __restrict__ found,
                            int n, unsigned tbits) {
    int node = blockIdx.x * blockDim.x + threadIdx.x;
    if (node == 0) *found = 0.0f;
    bool set = (node < n) && ((unsigned)(tbl[node] >> 32) >= tbits);
    unsigned long long mask = __ballot(set);
    if ((threadIdx.x & 63) == 0) {
        int w = node >> 6;
        if (w < ((n + 63) >> 6)) bmp[w] = mask;
    }
}

// Pass 3: low edges only; 16 stream loads upfront; bitmap fast-skip,
// shd slow path for unseeded nodes.
__global__ void main_pass(const float* __restrict__ pred,
                          const int* __restrict__ dst,
                          unsigned long long* __restrict__ tbl,
                          unsigned* __restrict__ shd,
                          const unsigned long long* __restrict__ bmp,
                          int e, int n, unsigned tbits) {
    extern __shared__ unsigned long long lbmp[];
    const int nwords = (n + 63) >> 6;
    for (int w = threadIdx.x; w < nwords; w += blockDim.x)
        lbmp[w] = bmp[w];
    __syncthreads();

    const int nvec = e >> 2;
    const int T = gridDim.x * blockDim.x;
    const int t = blockIdx.x * blockDim.x + threadIdx.x;

    fx4 p[CH];
    ix4 d[CH];
    int vi[CH];
    bool ok[CH];
    #pragma unroll
    for (int c = 0; c < CH; ++c) {
        vi[c] = t + c * T;
        ok[c] = vi[c] < nvec;
        int a = ok[c] ? vi[c] : 0;
        p[c] = ((const fx4*)pred)[a];
        d[c] = ((const ix4*)dst)[a];
    }

    #pragma unroll
    for (int c = 0; c < CH; ++c) {
        unsigned pbv[4] = {__float_as_uint(p[c].x), __float_as_uint(p[c].y),
                           __float_as_uint(p[c].z), __float_as_uint(p[c].w)};
        int dv[4] = {d[c].x, d[c].y, d[c].z, d[c].w};
        unsigned base = (unsigned)(vi[c] << 2);

        bool slow[4];
        unsigned cc[4] = {0, 0, 0, 0};
        #pragma unroll
        for (int k = 0; k < 4; ++k) {
            bool low = ok[c] && (pbv[k] < tbits);       // high edges done in seed
            bool seeded = (lbmp[dv[k] >> 6] >> (dv[k] & 63)) & 1ULL;
            slow[k] = low && !seeded;
        }
        #pragma unroll
        for (int k = 0; k < 4; ++k)
            if (slow[k]) cc[k] = shadow_ld(&shd[dv[k]]);   // MLP on residual
        #pragma unroll
        for (int k = 0; k < 4; ++k) {
            if (slow[k] && pbv[k] >= cc[k]) {
                (void)__hip_atomic_fetch_max(&tbl[dv[k]],
                                             pack64(pbv[k], base + k),
                                             __ATOMIC_RELAXED,
                                             __HIP_MEMORY_SCOPE_AGENT);
                shadow_st(&shd[dv[k]], pbv[k]);  // throttle unseeded cascades
            }
        }
    }

    // Tail (e % 4 edges): one thread, exact (idempotent max).
    if (blockIdx.x == 0 && threadIdx.x == 0) {
        for (int i = (nvec << 2); i < e; ++i) {
            unsigned pb_ = __float_as_uint(pred[i]);
            int dd = dst[i];
            if (pb_ >= shadow_ld(&shd[dd])) {
                (void)__hip_atomic_fetch_max(&tbl[dd], pack64(pb_, (unsigned)i),
                                             __ATOMIC_RELAXED,
                                             __HIP_MEMORY_SCOPE_AGENT);
                shadow_st(&shd[dd], pb_);
            }
        }
    }
}

__global__ void node_kernel(const unsigned long long* __restrict__ best,
                            const int* __restrict__ matched,
                            const int* __restrict__ src,
                            float* __restrict__ out_matched,
                            float* __restrict__ out_winpred,
                            float* __restrict__ found,
                            int n) {
    int i = blockIdx.x * blockDim.x + threadIdx.x;
    if (i >= n) return;
    unsigned long long b = best[i];
    int m = matched[i];
    int nm = m;
    float wp = 0.0f;
    if (b != 0ULL) {
        wp = __uint_as_float((unsigned int)(b >> 32));
        unsigned int idx = 0xFFFFFFFFu - (unsigned int)(b & 0xFFFFFFFFu);
        if (m == -1 && wp > 0.5f) {
            nm = matched[src[idx]];
            *found = 1.0f;   // benign race: every writer stores 1.0f
        }
    }
    out_matched[i] = (float)nm;
    out_winpred[i] = wp;
}

extern "C" void kernel_launch(void* const* d_in, const int* in_sizes, int n_in,
                              void* d_out, int out_size, void* d_ws, size_t ws_size,
                              hipStream_t stream) {
    const float* edge_pred = (const float*)d_in[0];
    const int*   edge_index = (const int*)d_in[1];   // [2, E]: row0 = src, row1 = dst
    const int*   matched   = (const int*)d_in[2];

    const int e = in_sizes[0];
    const int n = in_sizes[2];

    const int* src = edge_index;
    const int* dst = edge_index + e;

    // ws layout: [ u64 tbl[n] | u32 shd[n] | u64 bmp[ceil(n/64)] ]
    unsigned long long* tbl = (unsigned long long*)d_ws;
    unsigned* shd = (unsigned*)(tbl + n);
    unsigned long long* bmp = (unsigned long long*)(shd + n);
    const int nwords = (n + 63) >> 6;

    float* out_matched = (float*)d_out;
    float* out_winpred = out_matched + n;
    float* found       = out_matched + 2 * n;

    (void)hipMemsetAsync(tbl, 0, (size_t)n * 12, stream);  // tbl + shd

    float ts = 0.97f;
    unsigned tbits;
    memcpy(&tbits, &ts, sizeof(tbits));

    const int block = 256;
    const int nvec = e >> 2;

    int grid_e = ((nvec + CH - 1) / CH + block - 1) / block;
    if (grid_e < 1) grid_e = 1;

    seed_pass<<<grid_e, block, 0, stream>>>(edge_pred, dst, tbl, e, tbits);

    int grid_b = (n + block - 1) / block;
    bitmap_pass<<<grid_b, block, 0, stream>>>(tbl, bmp, found, n, tbits);

    const size_t lds_bytes = (size_t)nwords * sizeof(unsigned long long);
    main_pass<<<grid_e, block, lds_bytes, stream>>>(
        edge_pred, dst, tbl, shd, bmp, e, n, tbits);

    int grid_n = (n + 255) / 256;
    node_kernel<<<grid_n, 256, 0, stream>>>(tbl, matched, src,
                                            out_matched, out_winpred, found, n);
}

// Round 16
// 65.712 us; speedup vs baseline: 1.1160x; 1.1160x over previous
//
#include <hip/hip_runtime.h>
#include <string.h>

// Segmented argmax (first-max tie-break), exact, R10 structure (R14 tuning —
// best measured config, 66.0 us):
//  1. seed: stream pred (CH=4, loads upfront); edges >= t gather dst sparsely
//     and u64-atomicMax pack into tbl (unfiltered — atomics overlap stream;
//     R12 proved pre-filtering them costs more).
//  2. bitmap: bit i = (tbl[i]>>32) >= t; thread 0 zeroes `found`.
//  3. main (CH=4, loads upfront): high edge -> done in seed; low edge to
//     seeded node -> LDS-bitmap skip; low edge to unseeded node -> shd
//     plain-store-throttled filter + atomic.
//  4. node epilogue.
// Exactness: every >=t edge reaches the u64 atomicMax; skips require
// pred < t <= truemax (bitmap) or pred < shd <= truemax (slow path); equality
// always proceeds -> min-index tie-break via ~idx low word.
//
// Final model (verified by R14 prediction match; R15 falsified the last
// lever): filter-scans pace at ~3.5 TB/s; seed atomics hide under the
// stream; residual random loads ~300K/us; memory-side atomics ~26K/us.
// Tried and rejected: nt loads (R4), coop fusion (R11, 4x slower), seed
// filter (R12, +9us), CH=8 inner (R13), CH=8 upfront + block 256 (R15).

typedef float fx4 __attribute__((ext_vector_type(4)));
typedef int   ix4 __attribute__((ext_vector_type(4)));

#define CH 4    // vec4 chunks per thread (16 edges), loads issued upfront

__device__ __forceinline__ unsigned long long pack64(unsigned pbits, unsigned i) {
    return ((unsigned long long)pbits << 32) |
           (unsigned long long)(0xFFFFFFFFu - i);
}

__device__ __forceinline__ unsigned shadow_ld(const unsigned* p) {
    return __hip_atomic_load(p, __ATOMIC_RELAXED, __HIP_MEMORY_SCOPE_WORKGROUP);
}
__device__ __forceinline__ void shadow_st(unsigned* p, unsigned v) {
    __hip_atomic_store(p, v, __ATOMIC_RELAXED, __HIP_MEMORY_SCOPE_WORKGROUP);
}

// Pass 1: pred-only stream; high edges gather dst and atomicMax into tbl.
__global__ void seed_pass(const float* __restrict__ pred,
                          const int* __restrict__ dst,
                          unsigned long long* __restrict__ tbl,
                          int e, unsigned tbits) {
    const int nvec = e >> 2;
    const int T = gridDim.x * blockDim.x;
    const int t = blockIdx.x * blockDim.x + threadIdx.x;

    fx4 p[CH];
    int vi[CH];
    bool ok[CH];
    #pragma unroll
    for (int c = 0; c < CH; ++c) {
        vi[c] = t + c * T;
        ok[c] = vi[c] < nvec;
        p[c] = ((const fx4*)pred)[ok[c] ? vi[c] : 0];
    }
    #pragma unroll
    for (int c = 0; c < CH; ++c) {
        unsigned pbv[4] = {__float_as_uint(p[c].x), __float_as_uint(p[c].y),
                           __float_as_uint(p[c].z), __float_as_uint(p[c].w)};
        unsigned base = (unsigned)(vi[c] << 2);
        #pragma unroll
        for (int k = 0; k < 4; ++k) {
            if (ok[c] && pbv[k] >= tbits) {
                int d = dst[base + k];              // sparse gather (~3%)
                (void)__hip_atomic_fetch_max(&tbl[d], pack64(pbv[k], base + k),
                                             __ATOMIC_RELAXED,
                                             __HIP_MEMORY_SCOPE_AGENT);
            }
        }
    }
}

// Pass 2: bitmap from tbl — bit i set iff node i saw a >=t edge in seed.
// Thread 0 also zeroes `found` (replaces a 1-float memset dispatch).
__global__ void bitmap_pass(const unsigned long long* __restrict__ tbl,
                            unsigned long long* __restrict__ bmp,
                            float* __restrict__ found,
                            int n, unsigned tbits) {
    int node = blockIdx.x * blockDim.x + threadIdx.x;
    if (node == 0) *found = 0.0f;
    bool set = (node < n) && ((unsigned)(tbl[node] >> 32) >= tbits);
    unsigned long long mask = __ballot(set);
    if ((threadIdx.x & 63) == 0) {
        int w = node >> 6;
        if (w < ((n + 63) >> 6)) bmp[w] = mask;
    }
}

// Pass 3: low edges only; bitmap fast-skip, shd slow path for unseeded nodes.
__global__ void main_pass(const float* __restrict__ pred,
                          const int* __restrict__ dst,
                          unsigned long long* __restrict__ tbl,
                          unsigned* __restrict__ shd,
                          const unsigned long long* __restrict__ bmp,
                          int e, int n, unsigned tbits) {
    extern __shared__ unsigned long long lbmp[];
    const int nwords = (n + 63) >> 6;
    for (int w = threadIdx.x; w < nwords; w += blockDim.x)
        lbmp[w] = bmp[w];
    __syncthreads();

    const int nvec = e >> 2;
    const int T = gridDim.x * blockDim.x;
    const int t = blockIdx.x * blockDim.x + threadIdx.x;

    fx4 p[CH];
    ix4 d[CH];
    int vi[CH];
    bool ok[CH];
    #pragma unroll
    for (int c = 0; c < CH; ++c) {
        vi[c] = t + c * T;
        ok[c] = vi[c] < nvec;
        int a = ok[c] ? vi[c] : 0;
        p[c] = ((const fx4*)pred)[a];
        d[c] = ((const ix4*)dst)[a];
    }

    #pragma unroll
    for (int c = 0; c < CH; ++c) {
        unsigned pbv[4] = {__float_as_uint(p[c].x), __float_as_uint(p[c].y),
                           __float_as_uint(p[c].z), __float_as_uint(p[c].w)};
        int dv[4] = {d[c].x, d[c].y, d[c].z, d[c].w};
        unsigned base = (unsigned)(vi[c] << 2);

        bool slow[4];
        unsigned cc[4] = {0, 0, 0, 0};
        #pragma unroll
        for (int k = 0; k < 4; ++k) {
            bool low = ok[c] && (pbv[k] < tbits);       // high edges done in seed
            bool seeded = (lbmp[dv[k] >> 6] >> (dv[k] & 63)) & 1ULL;
            slow[k] = low && !seeded;
        }
        #pragma unroll
        for (int k = 0; k < 4; ++k)
            if (slow[k]) cc[k] = shadow_ld(&shd[dv[k]]);   // MLP on residual
        #pragma unroll
        for (int k = 0; k < 4; ++k) {
            if (slow[k] && pbv[k] >= cc[k]) {
                (void)__hip_atomic_fetch_max(&tbl[dv[k]],
                                             pack64(pbv[k], base + k),
                                             __ATOMIC_RELAXED,
                                             __HIP_MEMORY_SCOPE_AGENT);
                shadow_st(&shd[dv[k]], pbv[k]);  // throttle unseeded cascades
            }
        }
    }

    // Tail (e % 4 edges): one thread, exact (idempotent max).
    if (blockIdx.x == 0 && threadIdx.x == 0) {
        for (int i = (nvec << 2); i < e; ++i) {
            unsigned pb_ = __float_as_uint(pred[i]);
            int dd = dst[i];
            if (pb_ >= shadow_ld(&shd[dd])) {
                (void)__hip_atomic_fetch_max(&tbl[dd], pack64(pb_, (unsigned)i),
                                             __ATOMIC_RELAXED,
                                             __HIP_MEMORY_SCOPE_AGENT);
                shadow_st(&shd[dd], pb_);
            }
        }
    }
}

__global__ void node_kernel(const unsigned long long* __restrict__ best,
                            const int* __restrict__ matched,
                            const int* __restrict__ src,
                            float* __restrict__ out_matched,
                            float* __restrict__ out_winpred,
                            float* __restrict__ found,
                            int n) {
    int i = blockIdx.x * blockDim.x + threadIdx.x;
    if (i >= n) return;
    unsigned long long b = best[i];
    int m = matched[i];
    int nm = m;
    float wp = 0.0f;
    if (b != 0ULL) {
        wp = __uint_as_float((unsigned int)(b >> 32));
        unsigned int idx = 0xFFFFFFFFu - (unsigned int)(b & 0xFFFFFFFFu);
        if (m == -1 && wp > 0.5f) {
            nm = matched[src[idx]];
            *found = 1.0f;   // benign race: every writer stores 1.0f
        }
    }
    out_matched[i] = (float)nm;
    out_winpred[i] = wp;
}

extern "C" void kernel_launch(void* const* d_in, const int* in_sizes, int n_in,
                              void* d_out, int out_size, void* d_ws, size_t ws_size,
                              hipStream_t stream) {
    const float* edge_pred = (const float*)d_in[0];
    const int*   edge_index = (const int*)d_in[1];   // [2, E]: row0 = src, row1 = dst
    const int*   matched   = (const int*)d_in[2];

    const int e = in_sizes[0];
    const int n = in_sizes[2];

    const int* src = edge_index;
    const int* dst = edge_index + e;

    // ws layout: [ u64 tbl[n] | u32 shd[n] | u64 bmp[ceil(n/64)] ]
    unsigned long long* tbl = (unsigned long long*)d_ws;
    unsigned* shd = (unsigned*)(tbl + n);
    unsigned long long* bmp = (unsigned long long*)(shd + n);
    const int nwords = (n + 63) >> 6;

    float* out_matched = (float*)d_out;
    float* out_winpred = out_matched + n;
    float* found       = out_matched + 2 * n;

    (void)hipMemsetAsync(tbl, 0, (size_t)n * 12, stream);  // tbl + shd

    float ts = 0.97f;
    unsigned tbits;
    memcpy(&tbits, &ts, sizeof(tbits));

    const int block = 512;
    const int nvec = e >> 2;

    int grid_e = ((nvec + CH - 1) / CH + block - 1) / block;
    if (grid_e < 1) grid_e = 1;

    seed_pass<<<grid_e, block, 0, stream>>>(edge_pred, dst, tbl, e, tbits);

    int grid_b = (n + block - 1) / block;
    bitmap_pass<<<grid_b, block, 0, stream>>>(tbl, bmp, found, n, tbits);

    const size_t lds_bytes = (size_t)nwords * sizeof(unsigned long long);
    main_pass<<<grid_e, block, lds_bytes, stream>>>(
        edge_pred, dst, tbl, shd, bmp, e, n, tbits);

    int grid_n = (n + 255) / 256;
    node_kernel<<<grid_n, 256, 0, stream>>>(tbl, matched, src,
                                            out_matched, out_winpred, found, n);
}